// Round 8
// baseline (148.644 us; speedup 1.0000x reference)
//
#include <hip/hip_runtime.h>
#include <hip/hip_bf16.h>
#include <hip/hip_fp16.h>

#define L_LEN 16384
#define NB 64
#define NCHUNK 32
#define CHUNK 512

typedef short bf16x8 __attribute__((ext_vector_type(8)));
typedef float f32x4 __attribute__((ext_vector_type(4)));
typedef unsigned int u32x4 __attribute__((ext_vector_type(4)));

__device__ __forceinline__ unsigned short f2bf(float f) {
    unsigned u = __float_as_uint(f);
    return (unsigned short)((u + 0x7FFFu + ((u >> 16) & 1u)) >> 16);  // RNE
}

// packed RNE f32x2 -> bf16x2 (single instruction on gfx950)
__device__ __forceinline__ unsigned cvt_pk_bf16(float lo, float hi) {
    unsigned r;
    asm("v_cvt_pk_bf16_f32 %0, %1, %2" : "=v"(r) : "v"(lo), "v"(hi));
    return r;
}

// K0: blocks 0..63: W2 [128][128] f32 -> W2T [n][k] bf16 (transposed).
//     block 64: 512-entry PWL GELU table in T-DOMAIN: t = 32*p + 256, entry e covers
//     t in [e, e+1) i.e. p in [(e-256)/32, (e-255)/32). s' = g1-g0 (slope per unit t),
//     v' = g0 - s'*e, so g(p) ~= fma(s', t, v'). Slope continues linearly at both ends,
//     so clamped-index + UNCLAMPED-t extrapolation is exact.
__global__ __launch_bounds__(256) void k0_prep(const float* __restrict__ W2,
                                               unsigned short* __restrict__ w2t,
                                               float2* __restrict__ gtab) {
    if (blockIdx.x < 64) {
        int i = blockIdx.x * 256 + threadIdx.x;   // 0..16383
        int n = i >> 7, k = i & 127;
        w2t[i] = f2bf(W2[k * 128 + n]);
    } else {
        for (int e = threadIdx.x; e < 512; e += 256) {
            double p0 = ((double)e - 256.0) * (1.0 / 32.0);
            double p1 = p0 + (1.0 / 32.0);
            double g0 = 0.5 * p0 * (1.0 + erf(p0 * 0.7071067811865476));
            double g1 = 0.5 * p1 * (1.0 + erf(p1 * 0.7071067811865476));
            double s  = g1 - g0;
            double v  = g0 - s * (double)e;
            gtab[e] = make_float2((float)v, (float)s);
        }
    }
}

// K1: fused dx -> gelu(dx@W1+b1) in-register -> MFMA vs W2T -> gelu -> per-chunk sum/max
__global__ __launch_bounds__(256) void k1_fused(
    const float* __restrict__ x,
    const float* __restrict__ W1,
    const float* __restrict__ b1,
    const unsigned short* __restrict__ w2t,
    const float2* __restrict__ gtab,
    const float* __restrict__ b2,
    float* __restrict__ psum,
    float* __restrict__ pmaxf)
{
    __shared__ char   sW[32768];      // W2T bf16, XOR-swizzled (scratch overlaid at end)
    __shared__ float2 sTab[512];      // GELU LUT (t-domain)
    __shared__ float  sW1f[256];      // [2][128] f32, PRE-SCALED by 32
    __shared__ float  sb1f[128];      // 32*b1 + 256

    const int tid  = threadIdx.x;
    const int b    = blockIdx.x >> 5;
    const int c    = blockIdx.x & 31;
    const int lane = tid & 63;
    const int w    = tid >> 6;
    const int lr   = lane & 15;
    const int lk   = lane >> 4;
    const int swz  = (lr & 7) << 4;

    // stage W2T into LDS, swizzled: byte lb -> lb ^ ((row&7)<<4), row = lb>>8  (R5-proven)
    {
        const float4* src = (const float4*)w2t;  // 2048 x 16B
        #pragma unroll
        for (int it = 0; it < 8; ++it) {
            int cch = tid + it * 256;
            int dst = (cch << 4) ^ (((cch >> 4) & 7) << 4);
            *(float4*)(sW + dst) = src[cch];
        }
    }
    {   // GELU table: 256 threads x 16B = 4 KiB
        float4 v = ((const float4*)gtab)[tid];
        *(float4*)&sTab[tid * 2] = v;
    }
    if (tid < 128) {
        sW1f[tid]       = W1[tid] * 32.0f;
        sW1f[128 + tid] = W1[128 + tid] * 32.0f;
        sb1f[tid]       = fmaf(b1[tid], 32.0f, 256.0f);
    }
    __syncthreads();

    float b2t[8];   // 32*b2 + 256
    #pragma unroll
    for (int nt = 0; nt < 8; ++nt) b2t[nt] = fmaf(b2[nt * 16 + lr], 32.0f, 256.0f);

    float runS[8], runM[8];
    #pragma unroll
    for (int nt = 0; nt < 8; ++nt) { runS[nt] = 0.0f; runM[nt] = -3.0e38f; }

    const float2* xr  = (const float2*)x + (size_t)b * L_LEN;
    const int     tk0 = c * CHUNK + w * 128;

    const float* w0base = sW1f + lk * 8;
    const float* w1base = sW1f + 128 + lk * 8;
    const float* bbase  = sb1f + lk * 8;

    // t-domain LUT gelu: g = fma(s'[i], t, v'[i]); i = clamp((int)t, 0, 511); unclamped t extrapolates
    #define GELU_LUT_T(t, out) {                                        \
        float tc_ = __builtin_amdgcn_fmed3f((t), 0.0f, 511.0f);         \
        int   i_  = (int)tc_;                                           \
        float2 vs_ = sTab[i_];                                          \
        (out) = fmaf(vs_.y, (t), vs_.x);                                \
    }

    for (int it = 0; it < 4; ++it) {
        #pragma unroll
        for (int rb = 0; rb < 2; ++rb) {
            int g = tk0 + it * 32 + rb * 16 + lr;
            float2 a0 = xr[g];
            int gn = (g + 1) & (L_LEN - 1);           // circular roll (L is pow2)
            float2 a1 = xr[gn];
            float dx0 = a1.x - a0.x, dx1 = a1.y - a0.y;

            f32x4 acc[8];
            #pragma unroll
            for (int nt = 0; nt < 8; ++nt) acc[nt] = (f32x4){0.f, 0.f, 0.f, 0.f};

            #pragma unroll
            for (int kt = 0; kt < 4; ++kt) {
                // per-lane pre-scaled W1 slice from LDS (broadcast within lk group)
                float4 w0a = *(const float4*)(w0base + kt * 32);
                float4 w0b = *(const float4*)(w0base + kt * 32 + 4);
                float4 w1a = *(const float4*)(w1base + kt * 32);
                float4 w1b = *(const float4*)(w1base + kt * 32 + 4);
                float4 ba  = *(const float4*)(bbase  + kt * 32);
                float4 bb  = *(const float4*)(bbase  + kt * 32 + 4);

                float h[8];
                #pragma unroll
                for (int j = 0; j < 4; ++j) {
                    float t = fmaf(dx0, w0a[j], fmaf(dx1, w1a[j], ba[j]));  // t = 32p+256
                    GELU_LUT_T(t, h[j]);
                }
                #pragma unroll
                for (int j = 0; j < 4; ++j) {
                    float t = fmaf(dx0, w0b[j], fmaf(dx1, w1b[j], bb[j]));
                    GELU_LUT_T(t, h[4 + j]);
                }

                union { u32x4 u; bf16x8 v; } cv;
                cv.u = (u32x4){cvt_pk_bf16(h[0], h[1]), cvt_pk_bf16(h[2], h[3]),
                               cvt_pk_bf16(h[4], h[5]), cvt_pk_bf16(h[6], h[7])};
                bf16x8 aF = cv.v;

                #pragma unroll
                for (int nt = 0; nt < 8; ++nt) {
                    int bo = ((nt * 16 + lr) << 8) + kt * 64 + (lk << 4);
                    bo ^= swz;
                    bf16x8 bF = *(const bf16x8*)(sW + bo);
                    acc[nt] = __builtin_amdgcn_mfma_f32_16x16x32_bf16(aF, bF, acc[nt], 0, 0, 0);
                }
            }

            // epilogue: t = 32*(acc+b2)+256 via one fma; gelu; local sum/max (lk-reduce deferred)
            #pragma unroll
            for (int nt = 0; nt < 8; ++nt) {
                float v0, v1, v2, v3;
                float t0 = fmaf(acc[nt][0], 32.0f, b2t[nt]);
                float t1 = fmaf(acc[nt][1], 32.0f, b2t[nt]);
                float t2 = fmaf(acc[nt][2], 32.0f, b2t[nt]);
                float t3 = fmaf(acc[nt][3], 32.0f, b2t[nt]);
                GELU_LUT_T(t0, v0);
                GELU_LUT_T(t1, v1);
                GELU_LUT_T(t2, v2);
                GELU_LUT_T(t3, v3);
                runS[nt] += (v0 + v1) + (v2 + v3);
                runM[nt] = fmaxf(fmaxf(fmaxf(v0, v1), fmaxf(v2, v3)), runM[nt]);
            }
        }
    }

    // deferred cross-lk reduction (once)
    #pragma unroll
    for (int nt = 0; nt < 8; ++nt) {
        float s = runS[nt];
        s += __shfl_xor(s, 16, 64);
        s += __shfl_xor(s, 32, 64);
        float m = runM[nt];
        m = fmaxf(m, __shfl_xor(m, 16, 64));
        m = fmaxf(m, __shfl_xor(m, 32, 64));
        runS[nt] = s;
        runM[nt] = m;
    }

    // cross-wave combine — scratch overlays sW (all MFMA reads done; barrier first)
    __syncthreads();
    float* scrS = (float*)sW;            // [4][128]
    float* scrM = (float*)(sW + 2048);   // [4][128]
    if (lk == 0) {
        #pragma unroll
        for (int nt = 0; nt < 8; ++nt) {
            scrS[w * 128 + nt * 16 + lr] = runS[nt];
            scrM[w * 128 + nt * 16 + lr] = runM[nt];
        }
    }
    __syncthreads();
    if (tid < 128) {
        float s = (scrS[tid] + scrS[128 + tid]) + (scrS[256 + tid] + scrS[384 + tid]);
        float m = fmaxf(fmaxf(scrM[tid], scrM[128 + tid]), fmaxf(scrM[256 + tid], scrM[384 + tid]));
        int o = (b * NCHUNK + c) * 128 + tid;
        psum[o]  = s;
        pmaxf[o] = m;
    }
}

// K2: reduce chunks -> mean/max -> z = cat@Wh + bh -> LayerNorm -> out
__global__ __launch_bounds__(128) void k2_final(
    const float* __restrict__ psum,
    const float* __restrict__ pmaxf,
    const float* __restrict__ Wh,
    const float* __restrict__ bh,
    const float* __restrict__ gamma,
    const float* __restrict__ beta,
    float* __restrict__ out)
{
    __shared__ float cat[256];
    __shared__ float red[4];
    const int b = blockIdx.x, f = threadIdx.x;
    float s = 0.0f, m = -3.0e38f;
    #pragma unroll
    for (int c = 0; c < NCHUNK; ++c) {
        int o = (b * NCHUNK + c) * 128 + f;
        s += psum[o];
        m = fmaxf(m, pmaxf[o]);
    }
    cat[f]       = s * (1.0f / 16384.0f);
    cat[128 + f] = m;
    __syncthreads();

    float z = bh[f];
    #pragma unroll 4
    for (int j = 0; j < 256; ++j) z = fmaf(cat[j], Wh[j * 128 + f], z);

    float s1 = z, s2 = z * z;
    #pragma unroll
    for (int off = 32; off >= 1; off >>= 1) {
        s1 += __shfl_xor(s1, off, 64);
        s2 += __shfl_xor(s2, off, 64);
    }
    int lane = f & 63, wv = f >> 6;
    if (lane == 0) { red[wv] = s1; red[2 + wv] = s2; }
    __syncthreads();
    float S1 = red[0] + red[1], S2 = red[2] + red[3];
    float mu  = S1 * (1.0f / 128.0f);
    float var = S2 * (1.0f / 128.0f) - mu * mu;
    out[b * 128 + f] = (z - mu) * rsqrtf(var + 1e-5f) * gamma[f] + beta[f];
}

extern "C" void kernel_launch(void* const* d_in, const int* in_sizes, int n_in,
                              void* d_out, int out_size, void* d_ws, size_t ws_size,
                              hipStream_t stream) {
    const float* x     = (const float*)d_in[0];
    const float* W1    = (const float*)d_in[1];
    const float* b1    = (const float*)d_in[2];
    const float* W2    = (const float*)d_in[3];
    const float* b2    = (const float*)d_in[4];
    const float* Wh    = (const float*)d_in[5];
    const float* bh    = (const float*)d_in[6];
    const float* gamma = (const float*)d_in[7];
    const float* beta  = (const float*)d_in[8];
    float* out = (float*)d_out;

    char* wsb = (char*)d_ws;
    unsigned short* w2t = (unsigned short*)wsb;                         // 32 KiB
    float2* gtab = (float2*)(wsb + 32768);                              // 4 KiB
    float* psum  = (float*)(wsb + 36864);                               // 1 MiB
    float* pmaxf = (float*)(wsb + 36864 + NB * NCHUNK * 128 * 4);       // 1 MiB

    k0_prep<<<65, 256, 0, stream>>>(W2, w2t, gtab);
    k1_fused<<<NB * NCHUNK, 256, 0, stream>>>(x, W1, b1, w2t, gtab, b2, psum, pmaxf);
    k2_final<<<NB, 128, 0, stream>>>(psum, pmaxf, Wh, bh, gamma, beta, out);
}

// Round 9
// 107.304 us; speedup vs baseline: 1.3853x; 1.3853x over previous
//
#include <hip/hip_runtime.h>
#include <hip/hip_bf16.h>
#include <hip/hip_fp16.h>

#define L_LEN 16384
#define NB 64
#define NCHUNK 32
#define CHUNK 512

typedef short bf16x8 __attribute__((ext_vector_type(8)));
typedef float f32x4 __attribute__((ext_vector_type(4)));
typedef unsigned int u32x4 __attribute__((ext_vector_type(4)));

__device__ __forceinline__ unsigned short f2bf(float f) {
    unsigned u = __float_as_uint(f);
    return (unsigned short)((u + 0x7FFFu + ((u >> 16) & 1u)) >> 16);  // RNE
}

// packed RNE f32x2 -> bf16x2 (single instruction on gfx950)
__device__ __forceinline__ unsigned cvt_pk_bf16(float lo, float hi) {
    unsigned r;
    asm("v_cvt_pk_bf16_f32 %0, %1, %2" : "=v"(r) : "v"(lo), "v"(hi));
    return r;
}

// tanh-form GELU via sigmoid: x / (1 + exp2(x*(c1 + c2*x^2)))
__device__ __forceinline__ float gelu_s(float x) {
    float x2 = x * x;
    float f  = x * fmaf(-0.1029437f, x2, -2.30220789f);
    float e  = __builtin_amdgcn_exp2f(f);
    return x * __builtin_amdgcn_rcpf(1.0f + e);
}

// K0: blocks 0..63: W2 [128][128] f32 -> W2T [n][k] bf16 (transposed).
//     block 64: build 512-entry piecewise-linear GELU table over [-8,8), step 1/32.
//     Entry i: s = (g(x_{i+1})-g(x_i))*32 ; v' = g(x_i) - s*x_i  =>  g(p) ~= fma(s, p, v').
//     Slope->1 (x>8) and ->0 (x<-8) make extrapolation exact for clamped indices.
__global__ __launch_bounds__(256) void k0_prep(const float* __restrict__ W2,
                                               unsigned short* __restrict__ w2t,
                                               float2* __restrict__ gtab) {
    if (blockIdx.x < 64) {
        int i = blockIdx.x * 256 + threadIdx.x;   // 0..16383
        int n = i >> 7, k = i & 127;
        w2t[i] = f2bf(W2[k * 128 + n]);
    } else {
        for (int e = threadIdx.x; e < 512; e += 256) {
            double x0 = (double)e * (1.0 / 32.0) - 8.0;
            double x1 = x0 + (1.0 / 32.0);
            double g0 = 0.5 * x0 * (1.0 + erf(x0 * 0.7071067811865476));
            double g1 = 0.5 * x1 * (1.0 + erf(x1 * 0.7071067811865476));
            double s  = (g1 - g0) * 32.0;
            double v  = g0 - s * x0;
            gtab[e] = make_float2((float)v, (float)s);
        }
    }
}

// K1: fused dx -> gelu(dx@W1+b1) in-register -> MFMA vs W2T -> gelu -> per-chunk sum/max
__global__ __launch_bounds__(256) void k1_fused(
    const float* __restrict__ x,
    const float* __restrict__ W1,
    const float* __restrict__ b1,
    const unsigned short* __restrict__ w2t,
    const float2* __restrict__ gtab,
    const float* __restrict__ b2,
    float* __restrict__ psum,
    float* __restrict__ pmaxf)
{
    __shared__ char   sW[32768];      // W2T bf16, XOR-swizzled (scratch overlaid at end)
    __shared__ float2 sTab[512];      // GELU LUT
    __shared__ float  sW1f[256];      // [2][128] f32
    __shared__ float  sb1f[128];

    const int tid  = threadIdx.x;
    const int b    = blockIdx.x >> 5;
    const int c    = blockIdx.x & 31;
    const int lane = tid & 63;
    const int w    = tid >> 6;
    const int lr   = lane & 15;
    const int lk   = lane >> 4;
    const int swz  = (lr & 7) << 4;

    // stage W2T into LDS, swizzled: byte lb -> lb ^ ((row&7)<<4), row = lb>>8
    {
        const float4* src = (const float4*)w2t;  // 2048 x 16B
        #pragma unroll
        for (int it = 0; it < 8; ++it) {
            int cch = tid + it * 256;
            int dst = (cch << 4) ^ (((cch >> 4) & 7) << 4);
            *(float4*)(sW + dst) = src[cch];
        }
    }
    {   // GELU table: 256 threads x 16B = 4 KiB
        float4 v = ((const float4*)gtab)[tid];
        *(float4*)&sTab[tid * 2] = v;
    }
    if (tid < 128) {
        sW1f[tid]       = W1[tid];
        sW1f[128 + tid] = W1[128 + tid];
        sb1f[tid]       = b1[tid];
    }
    __syncthreads();

    float b2r[8];
    #pragma unroll
    for (int nt = 0; nt < 8; ++nt) b2r[nt] = b2[nt * 16 + lr];

    float runS[8], runM[8];
    #pragma unroll
    for (int nt = 0; nt < 8; ++nt) { runS[nt] = 0.0f; runM[nt] = -3.0e38f; }

    const float2* xr  = (const float2*)x + (size_t)b * L_LEN;
    const int     tk0 = c * CHUNK + w * 128;

    const float* w0base = sW1f + lk * 8;
    const float* w1base = sW1f + 128 + lk * 8;
    const float* bbase  = sb1f + lk * 8;

    // LUT gelu: g(p) = fma(s[i], p, v'[i]), i = clamp-index; extrapolation exact at both ends
    #define GELU_LUT(p, out) {                                          \
        float xm_ = __builtin_amdgcn_fmed3f((p), -8.0f, 7.96875f);      \
        float t_  = fmaf(xm_, 32.0f, 256.0f);                           \
        int   i_  = (int)t_;                                            \
        float2 vs_ = sTab[i_];                                          \
        (out) = fmaf(vs_.y, (p), vs_.x);                                \
    }

    for (int it = 0; it < 4; ++it) {
        #pragma unroll
        for (int rb = 0; rb < 2; ++rb) {
            int g = tk0 + it * 32 + rb * 16 + lr;
            float2 a0 = xr[g];
            int gn = (g + 1) & (L_LEN - 1);           // circular roll (L pow2)
            float2 a1 = xr[gn];
            float dx0 = a1.x - a0.x, dx1 = a1.y - a0.y;

            f32x4 acc[8];
            #pragma unroll
            for (int nt = 0; nt < 8; ++nt) acc[nt] = (f32x4){0.f, 0.f, 0.f, 0.f};

            #pragma unroll
            for (int kt = 0; kt < 4; ++kt) {
                // per-lane W1 slice from LDS (broadcast within lk group)
                float4 w0a = *(const float4*)(w0base + kt * 32);
                float4 w0b = *(const float4*)(w0base + kt * 32 + 4);
                float4 w1a = *(const float4*)(w1base + kt * 32);
                float4 w1b = *(const float4*)(w1base + kt * 32 + 4);
                float4 ba  = *(const float4*)(bbase  + kt * 32);
                float4 bb  = *(const float4*)(bbase  + kt * 32 + 4);

                float h[8];
                #pragma unroll
                for (int j = 0; j < 4; ++j) {
                    float p = fmaf(dx0, w0a[j], fmaf(dx1, w1a[j], ba[j]));
                    GELU_LUT(p, h[j]);
                }
                #pragma unroll
                for (int j = 0; j < 4; ++j) {
                    float p = fmaf(dx0, w0b[j], fmaf(dx1, w1b[j], bb[j]));
                    GELU_LUT(p, h[4 + j]);
                }

                union { u32x4 u; bf16x8 v; } cv;
                cv.u = (u32x4){cvt_pk_bf16(h[0], h[1]), cvt_pk_bf16(h[2], h[3]),
                               cvt_pk_bf16(h[4], h[5]), cvt_pk_bf16(h[6], h[7])};
                bf16x8 aF = cv.v;

                #pragma unroll
                for (int nt = 0; nt < 8; ++nt) {
                    int bo = ((nt * 16 + lr) << 8) + kt * 64 + (lk << 4);
                    bo ^= swz;
                    bf16x8 bF = *(const bf16x8*)(sW + bo);
                    acc[nt] = __builtin_amdgcn_mfma_f32_16x16x32_bf16(aF, bF, acc[nt], 0, 0, 0);
                }
            }

            // epilogue: +b2, sigma-form gelu (VALU/trans pipes — off the LDS pipe)
            #pragma unroll
            for (int nt = 0; nt < 8; ++nt) {
                float v0 = gelu_s(acc[nt][0] + b2r[nt]);
                float v1 = gelu_s(acc[nt][1] + b2r[nt]);
                float v2 = gelu_s(acc[nt][2] + b2r[nt]);
                float v3 = gelu_s(acc[nt][3] + b2r[nt]);
                runS[nt] += (v0 + v1) + (v2 + v3);
                runM[nt] = fmaxf(fmaxf(fmaxf(v0, v1), fmaxf(v2, v3)), runM[nt]);
            }
        }
    }

    // deferred cross-lk reduction (once)
    #pragma unroll
    for (int nt = 0; nt < 8; ++nt) {
        float s = runS[nt];
        s += __shfl_xor(s, 16, 64);
        s += __shfl_xor(s, 32, 64);
        float m = runM[nt];
        m = fmaxf(m, __shfl_xor(m, 16, 64));
        m = fmaxf(m, __shfl_xor(m, 32, 64));
        runS[nt] = s;
        runM[nt] = m;
    }

    // cross-wave combine — scratch overlays sW (all MFMA reads done; barrier first)
    __syncthreads();
    float* scrS = (float*)sW;            // [4][128]
    float* scrM = (float*)(sW + 2048);   // [4][128]
    if (lk == 0) {
        #pragma unroll
        for (int nt = 0; nt < 8; ++nt) {
            scrS[w * 128 + nt * 16 + lr] = runS[nt];
            scrM[w * 128 + nt * 16 + lr] = runM[nt];
        }
    }
    __syncthreads();
    if (tid < 128) {
        float s = (scrS[tid] + scrS[128 + tid]) + (scrS[256 + tid] + scrS[384 + tid]);
        float m = fmaxf(fmaxf(scrM[tid], scrM[128 + tid]), fmaxf(scrM[256 + tid], scrM[384 + tid]));
        int o = (b * NCHUNK + c) * 128 + tid;
        psum[o]  = s;
        pmaxf[o] = m;
    }
}

// K2: reduce chunks -> mean/max -> z = cat@Wh + bh -> LayerNorm -> out
__global__ __launch_bounds__(128) void k2_final(
    const float* __restrict__ psum,
    const float* __restrict__ pmaxf,
    const float* __restrict__ Wh,
    const float* __restrict__ bh,
    const float* __restrict__ gamma,
    const float* __restrict__ beta,
    float* __restrict__ out)
{
    __shared__ float cat[256];
    __shared__ float red[4];
    const int b = blockIdx.x, f = threadIdx.x;
    float s = 0.0f, m = -3.0e38f;
    #pragma unroll
    for (int c = 0; c < NCHUNK; ++c) {
        int o = (b * NCHUNK + c) * 128 + f;
        s += psum[o];
        m = fmaxf(m, pmaxf[o]);
    }
    cat[f]       = s * (1.0f / 16384.0f);
    cat[128 + f] = m;
    __syncthreads();

    float z = bh[f];
    #pragma unroll 4
    for (int j = 0; j < 256; ++j) z = fmaf(cat[j], Wh[j * 128 + f], z);

    float s1 = z, s2 = z * z;
    #pragma unroll
    for (int off = 32; off >= 1; off >>= 1) {
        s1 += __shfl_xor(s1, off, 64);
        s2 += __shfl_xor(s2, off, 64);
    }
    int lane = f & 63, wv = f >> 6;
    if (lane == 0) { red[wv] = s1; red[2 + wv] = s2; }
    __syncthreads();
    float S1 = red[0] + red[1], S2 = red[2] + red[3];
    float mu  = S1 * (1.0f / 128.0f);
    float var = S2 * (1.0f / 128.0f) - mu * mu;
    out[b * 128 + f] = (z - mu) * rsqrtf(var + 1e-5f) * gamma[f] + beta[f];
}

extern "C" void kernel_launch(void* const* d_in, const int* in_sizes, int n_in,
                              void* d_out, int out_size, void* d_ws, size_t ws_size,
                              hipStream_t stream) {
    const float* x     = (const float*)d_in[0];
    const float* W1    = (const float*)d_in[1];
    const float* b1    = (const float*)d_in[2];
    const float* W2    = (const float*)d_in[3];
    const float* b2    = (const float*)d_in[4];
    const float* Wh    = (const float*)d_in[5];
    const float* bh    = (const float*)d_in[6];
    const float* gamma = (const float*)d_in[7];
    const float* beta  = (const float*)d_in[8];
    float* out = (float*)d_out;

    char* wsb = (char*)d_ws;
    unsigned short* w2t = (unsigned short*)wsb;                         // 32 KiB
    float2* gtab = (float2*)(wsb + 32768);                              // 4 KiB
    float* psum  = (float*)(wsb + 36864);                               // 1 MiB
    float* pmaxf = (float*)(wsb + 36864 + NB * NCHUNK * 128 * 4);       // 1 MiB

    k0_prep<<<65, 256, 0, stream>>>(W2, w2t, gtab);
    k1_fused<<<NB * NCHUNK, 256, 0, stream>>>(x, W1, b1, w2t, gtab, b2, psum, pmaxf);
    k2_final<<<NB, 128, 0, stream>>>(psum, pmaxf, Wh, bh, gamma, beta, out);
}